// Round 1
// baseline (1183.121 us; speedup 1.0000x reference)
//
#include <hip/hip_runtime.h>
#include <cstddef>

#define NB 256   // batch
#define NT 512   // time
#define ND 128   // input dim
#define NH 128   // hidden
#define NG 512   // 4*H

constexpr float F_EPS  = 1e-7f;
constexpr float F_TEMP = 0.1f;

__device__ __forceinline__ float sig(float x) { return 1.0f / (1.0f + expf(-x)); }

// ---------------- kernel 1: scalar regularization outputs ----------------
__global__ void k_scalars(const float* __restrict__ wih, const float* __restrict__ whh,
                          const float* __restrict__ bih, const float* __restrict__ bhh,
                          const float* __restrict__ pl, const float* __restrict__ plr,
                          float* __restrict__ out_tail) {
    __shared__ float red[3][8];
    int t = threadIdx.x;  // 512 threads
    float sk = 0.f, sr = 0.f, sb = 0.f;
    for (int i = t; i < NG * ND; i += 512) { float v = wih[i]; sk += v * v; }
    for (int i = t; i < NG * NH; i += 512) { float v = whh[i]; sr += v * v; }
    { float v = bih[t], w2 = bhh[t]; sb = v * v + w2 * w2; }  // t covers 0..511 exactly
    for (int off = 32; off; off >>= 1) {
        sk += __shfl_down(sk, off);
        sr += __shfl_down(sr, off);
        sb += __shfl_down(sb, off);
    }
    int wid = t >> 6, lane = t & 63;
    if (lane == 0) { red[0][wid] = sk; red[1][wid] = sr; red[2][wid] = sb; }
    __syncthreads();
    if (t == 0) {
        float SK = 0.f, SR = 0.f, SB = 0.f;
        for (int i = 0; i < 8; i++) { SK += red[0][i]; SR += red[1][i]; SB += red[2][i]; }
        float p  = sig(pl[0]);
        float pr = sig(plr[0]);
        float wr = 1e-6f * (SK / (1.f - p) + SR / (1.f - pr));
        float br = 1e-6f * SB;
        float ek = p * logf(p) + (1.f - p) * logf(1.f - p);
        float er = pr * logf(pr) + (1.f - pr) * logf(1.f - pr);
        float dr = 1e-5f * ((float)ND * ek + (float)NH * er);
        out_tail[0] = wr + br + dr;  // regularization
        out_tail[1] = p;
        out_tail[2] = pr;
    }
}

// ---------------- kernel 2: input GEMM  G = (x*mask_x/(1-p)) @ W_ih^T + b ----------------
// 64x64 tile, K=128 in one shot, XOR-swizzled LDS (slot ^ (row>>2)&7) for
// conflict-free ds_read_b128 on both operands.
__global__ __launch_bounds__(256) void k_gemm(const float* __restrict__ x,
        const float* __restrict__ wih, const float* __restrict__ bih,
        const float* __restrict__ bhh, const float* __restrict__ pl,
        const float* __restrict__ unif_x, float* __restrict__ G) {
    __shared__ float As[64 * 128];
    __shared__ float Ws[64 * 128];
    __shared__ float sx[128];
    __shared__ float bsum[64];
    int t  = threadIdx.x;
    int m0 = blockIdx.x * 64;   // row block (within one batch b: 64 | 512)
    int j0 = blockIdx.y * 64;   // col block
    int b  = m0 >> 9;           // m0 / 512

    float p = sig(pl[0]);
    if (t < 128) {
        float u  = unif_x[b * ND + t];
        float lg = logf(p + F_EPS) - logf(1.f - p + F_EPS)
                 + logf(u + F_EPS) - logf(1.f - u + F_EPS);
        float mk = 1.f - sig(lg / F_TEMP);
        sx[t] = mk / (1.f - p);
    } else if (t < 192) {
        int j = t - 128;
        bsum[j] = bih[j0 + j] + bhh[j0 + j];
    }
    __syncthreads();

    // stage A (scaled) and W tiles: 2048 float4 each, 8 per thread
#pragma unroll
    for (int r8 = 0; r8 < 8; r8++) {
        int flat = r8 * 256 + t;          // float4 index 0..2047
        int row = flat >> 5, slot = flat & 31;
        float4 a = *(const float4*)(x + ((size_t)(m0 + row)) * ND + slot * 4);
        float4 s = *(const float4*)(sx + slot * 4);
        a.x *= s.x; a.y *= s.y; a.z *= s.z; a.w *= s.w;
        int ss = slot ^ ((row >> 2) & 7);
        *(float4*)(As + row * 128 + ss * 4) = a;
        float4 wv = *(const float4*)(wih + ((size_t)(j0 + row)) * ND + slot * 4);
        *(float4*)(Ws + row * 128 + ss * 4) = wv;
    }
    __syncthreads();

    int tx = t & 15, ty = t >> 4;
    float acc[4][4] = {};
#pragma unroll
    for (int slot = 0; slot < 32; slot++) {
        float4 av[4], wv[4];
#pragma unroll
        for (int i = 0; i < 4; i++) {
            int r  = ty * 4 + i;
            av[i] = *(const float4*)(As + r * 128 + (slot ^ ((r >> 2) & 7)) * 4);
            int rw = tx * 4 + i;
            wv[i] = *(const float4*)(Ws + rw * 128 + (slot ^ ((rw >> 2) & 7)) * 4);
        }
#pragma unroll
        for (int i = 0; i < 4; i++)
#pragma unroll
            for (int q = 0; q < 4; q++)
                acc[i][q] += av[i].x * wv[q].x + av[i].y * wv[q].y
                           + av[i].z * wv[q].z + av[i].w * wv[q].w;
    }

    float4 bs = *(const float4*)(bsum + tx * 4);
#pragma unroll
    for (int i = 0; i < 4; i++) {
        float4 o;
        o.x = acc[i][0] + bs.x; o.y = acc[i][1] + bs.y;
        o.z = acc[i][2] + bs.z; o.w = acc[i][3] + bs.w;
        *(float4*)(G + ((size_t)(m0 + ty * 4 + i)) * NG + j0 + tx * 4) = o;
    }
}

// ---------------- kernel 3: recurrence, one block per batch row ----------------
// Thread j (0..511) owns gate row j: W_hh[j,:] in 128 VGPRs. h,c persist in
// registers of threads n<128. Gate exchange via LDS, 2 barriers/step.
__global__ __launch_bounds__(512, 2) void k_lstm(const float* __restrict__ G,
        const float* __restrict__ whh, const float* __restrict__ plr,
        const float* __restrict__ unif_h,
        float* __restrict__ xout, float* __restrict__ hlast) {
    __shared__ float hd[128];
    __shared__ float gates[512];
    int b = blockIdx.x;
    int j = threadIdx.x;

    float w[128];
#pragma unroll
    for (int k4 = 0; k4 < 32; k4++) {
        float4 v = *(const float4*)(whh + (size_t)j * NH + k4 * 4);
        w[4 * k4 + 0] = v.x; w[4 * k4 + 1] = v.y;
        w[4 * k4 + 2] = v.z; w[4 * k4 + 3] = v.w;
    }

    float pr = sig(plr[0]);
    float h = 0.f, c = 0.f, msk = 0.f;
    if (j < 128) {
        float u  = unif_h[b * NH + j];
        float lg = logf(pr + F_EPS) - logf(1.f - pr + F_EPS)
                 + logf(u + F_EPS) - logf(1.f - u + F_EPS);
        float mk = 1.f - sig(lg / F_TEMP);
        msk = mk / (1.f - pr);
        hd[j] = 0.f;
    }
    const float* Gp = G + ((size_t)b * NT) * NG + j;
    float gnext = Gp[0];
    __syncthreads();

    for (int t = 0; t < NT; t++) {
        float cur = gnext;
        if (t + 1 < NT) gnext = Gp[(size_t)(t + 1) * NG];  // prefetch next step
        float a0 = 0.f, a1 = 0.f, a2 = 0.f, a3 = 0.f;
#pragma unroll
        for (int k4 = 0; k4 < 32; k4++) {
            float4 hv = *(const float4*)(hd + 4 * k4);  // broadcast read
            a0 += w[4 * k4 + 0] * hv.x;
            a1 += w[4 * k4 + 1] * hv.y;
            a2 += w[4 * k4 + 2] * hv.z;
            a3 += w[4 * k4 + 3] * hv.w;
        }
        float g = cur + ((a0 + a1) + (a2 + a3));
        float act;
        if ((j >> 7) == 2) act = tanhf(g);           // g-gate rows 256..383 (wave-uniform)
        else               act = 1.f / (1.f + expf(-g));
        gates[j] = act;
        __syncthreads();   // barrier 1: gates ready, hd reads done
        if (j < 128) {
            float ig = gates[j], fg = gates[j + 128];
            float gg = gates[j + 256], og = gates[j + 384];
            c = fg * c + ig * gg;
            h = og * tanhf(c);
            hd[j] = h * msk;
            xout[((size_t)b * NT + t) * NH + j] = h;
        }
        __syncthreads();   // barrier 2: hd ready for next step
    }
    if (j < 128) hlast[(size_t)b * NH + j] = h;
}

extern "C" void kernel_launch(void* const* d_in, const int* in_sizes, int n_in,
                              void* d_out, int out_size, void* d_ws, size_t ws_size,
                              hipStream_t stream) {
    const float* x   = (const float*)d_in[0];
    const float* wih = (const float*)d_in[1];
    const float* whh = (const float*)d_in[2];
    const float* bih = (const float*)d_in[3];
    const float* bhh = (const float*)d_in[4];
    const float* pl  = (const float*)d_in[5];
    const float* plr = (const float*)d_in[6];
    const float* ux  = (const float*)d_in[7];
    const float* uh  = (const float*)d_in[8];

    float* out   = (float*)d_out;
    float* xout  = out;                                 // [B,T,H]
    float* hlast = out + (size_t)NB * NT * NH;          // [B,H]
    float* tail  = hlast + (size_t)NB * NH;             // reg, p, p_rec

    float* G = (float*)d_ws;  // [B*T, 4H] f32 = 256 MB scratch

    k_scalars<<<1, 512, 0, stream>>>(wih, whh, bih, bhh, pl, plr, tail);

    dim3 gg(NB * NT / 64, NG / 64);
    k_gemm<<<gg, 256, 0, stream>>>(x, wih, bih, bhh, pl, ux, G);

    k_lstm<<<NB, 512, 0, stream>>>(G, whh, plr, uh, xout, hlast);
}

// Round 2
// 731.713 us; speedup vs baseline: 1.6169x; 1.6169x over previous
//
#include <hip/hip_runtime.h>
#include <cstddef>

#define NB 256   // batch
#define NT 512   // time
#define ND 128   // input dim
#define NH 128   // hidden
#define NG 512   // 4*H
#define NM (NB * NT)   // 131072 rows of the input GEMM

constexpr float F_EPS  = 1e-7f;
constexpr float F_TEMP = 0.1f;

typedef _Float16 h2_t __attribute__((ext_vector_type(2)));
typedef _Float16 h4_t __attribute__((ext_vector_type(4)));
typedef _Float16 h8_t __attribute__((ext_vector_type(8)));
typedef float    fx4  __attribute__((ext_vector_type(4)));

#if defined(__has_builtin)
#  if __has_builtin(__builtin_amdgcn_fdot2)
#    define FDOT2(a, b, c) __builtin_amdgcn_fdot2((a), (b), (c), false)
#  endif
#endif
#ifndef FDOT2
#  define FDOT2(a, b, c) ((c) + (float)(a)[0] * (float)(b)[0] + (float)(a)[1] * (float)(b)[1])
#endif

__device__ __forceinline__ float sig(float x) { return 1.0f / (1.0f + expf(-x)); }

// ---------------- kernel 1: scalar regularization outputs (unchanged, proven) ----
__global__ void k_scalars(const float* __restrict__ wih, const float* __restrict__ whh,
                          const float* __restrict__ bih, const float* __restrict__ bhh,
                          const float* __restrict__ pl, const float* __restrict__ plr,
                          float* __restrict__ out_tail) {
    __shared__ float red[3][8];
    int t = threadIdx.x;  // 512 threads
    float sk = 0.f, sr = 0.f, sb = 0.f;
    for (int i = t; i < NG * ND; i += 512) { float v = wih[i]; sk += v * v; }
    for (int i = t; i < NG * NH; i += 512) { float v = whh[i]; sr += v * v; }
    { float v = bih[t], w2 = bhh[t]; sb = v * v + w2 * w2; }
    for (int off = 32; off; off >>= 1) {
        sk += __shfl_down(sk, off);
        sr += __shfl_down(sr, off);
        sb += __shfl_down(sb, off);
    }
    int wid = t >> 6, lane = t & 63;
    if (lane == 0) { red[0][wid] = sk; red[1][wid] = sr; red[2][wid] = sb; }
    __syncthreads();
    if (t == 0) {
        float SK = 0.f, SR = 0.f, SB = 0.f;
        for (int i = 0; i < 8; i++) { SK += red[0][i]; SR += red[1][i]; SB += red[2][i]; }
        float p  = sig(pl[0]);
        float pr = sig(plr[0]);
        float wr = 1e-6f * (SK / (1.f - p) + SR / (1.f - pr));
        float br = 1e-6f * SB;
        float ek = p * logf(p) + (1.f - p) * logf(1.f - p);
        float er = pr * logf(pr) + (1.f - pr) * logf(1.f - pr);
        float dr = 1e-5f * ((float)ND * ek + (float)NH * er);
        out_tail[0] = wr + br + dr;
        out_tail[1] = p;
        out_tail[2] = pr;
    }
}

// ---------------- kernel 1b: f32 -> f16 weight conversion ----------------
__global__ __launch_bounds__(256) void k_convert(const float* __restrict__ wih,
        const float* __restrict__ whh, _Float16* __restrict__ wih_h,
        _Float16* __restrict__ whh_h) {
    int i = blockIdx.x * 256 + threadIdx.x;    // float4 index, 16384 total
    float4 a = ((const float4*)wih)[i];
    float4 b = ((const float4*)whh)[i];
    h4_t ah, bh;
    ah[0] = (_Float16)a.x; ah[1] = (_Float16)a.y; ah[2] = (_Float16)a.z; ah[3] = (_Float16)a.w;
    bh[0] = (_Float16)b.x; bh[1] = (_Float16)b.y; bh[2] = (_Float16)b.z; bh[3] = (_Float16)b.w;
    *(h4_t*)(wih_h + 4 * (size_t)i) = ah;
    *(h4_t*)(whh_h + 4 * (size_t)i) = bh;
}

// ---------------- kernel 2: f16 MFMA input GEMM ----------------
// G'[j][m] (f16, m-major rows) = sum_k (x[m,k]*mask_x[b,k]/(1-p)) * Wih[j,k] + bih[j]+bhh[j]
// 128x128 tile, K=128 staged once, XOR swizzle ((s16 ^ (row&7)) on 16B slots).
__global__ __launch_bounds__(256, 2) void k_gemm(const float* __restrict__ x,
        const _Float16* __restrict__ wih_h, const float* __restrict__ bih,
        const float* __restrict__ bhh, const float* __restrict__ pl,
        const float* __restrict__ unif_x, _Float16* __restrict__ Gp) {
    __shared__ _Float16 Alds[128 * 128];
    __shared__ _Float16 Wlds[128 * 128];
    __shared__ float sx[128];
    __shared__ float bsum[128];
    int t  = threadIdx.x;
    int m0 = blockIdx.x * 128;           // row block (within one batch b: 128 | 512)
    int j0 = blockIdx.y * 128;           // gate-col block
    int b  = m0 >> 9;

    float p = sig(pl[0]);
    if (t < 128) {
        float u  = unif_x[b * ND + t];
        float lg = logf(p + F_EPS) - logf(1.f - p + F_EPS)
                 + logf(u + F_EPS) - logf(1.f - u + F_EPS);
        float mk = 1.f - sig(lg / F_TEMP);
        sx[t] = mk / (1.f - p);
    } else {
        int j = t - 128;
        bsum[j] = bih[j0 + j] + bhh[j0 + j];
    }
    __syncthreads();

    // stage A (x * sx -> f16) and W tiles: 2048 16B slots each, 8 per thread
#pragma unroll
    for (int i = 0; i < 8; i++) {
        int s   = i * 256 + t;
        int row = s >> 4;                 // 0..127
        int s16 = s & 15;                 // 16B slot within row
        const float4* xp = (const float4*)(x + (size_t)(m0 + row) * ND + s16 * 8);
        float4 v0 = xp[0], v1 = xp[1];
        float4 s0 = *(const float4*)(sx + s16 * 8);
        float4 s1 = *(const float4*)(sx + s16 * 8 + 4);
        h8_t hv;
        hv[0] = (_Float16)(v0.x * s0.x); hv[1] = (_Float16)(v0.y * s0.y);
        hv[2] = (_Float16)(v0.z * s0.z); hv[3] = (_Float16)(v0.w * s0.w);
        hv[4] = (_Float16)(v1.x * s1.x); hv[5] = (_Float16)(v1.y * s1.y);
        hv[6] = (_Float16)(v1.z * s1.z); hv[7] = (_Float16)(v1.w * s1.w);
        *(h8_t*)(&Alds[(size_t)row * 128 + ((s16 ^ (row & 7)) << 3)]) = hv;
        h8_t wv = *(const h8_t*)(wih_h + (size_t)(j0 + row) * ND + s16 * 8);
        *(h8_t*)(&Wlds[(size_t)row * 128 + ((s16 ^ (row & 7)) << 3)]) = wv;
    }
    __syncthreads();

    int w  = t >> 6, l = t & 63;
    int lr = l & 15, lg = l >> 4;
    fx4 acc[2][8] = {};
#pragma unroll
    for (int kk = 0; kk < 4; kk++) {
        h8_t af[2], bf[8];
#pragma unroll
        for (int mt = 0; mt < 2; mt++) {
            int r = 32 * w + 16 * mt + lr;
            af[mt] = *(const h8_t*)(&Alds[(size_t)r * 128 + (((4 * kk + lg) ^ (r & 7)) << 3)]);
        }
#pragma unroll
        for (int nt = 0; nt < 8; nt++) {
            int r = 16 * nt + lr;
            bf[nt] = *(const h8_t*)(&Wlds[(size_t)r * 128 + (((4 * kk + lg) ^ (r & 7)) << 3)]);
        }
#pragma unroll
        for (int mt = 0; mt < 2; mt++)
#pragma unroll
            for (int nt = 0; nt < 8; nt++)
                acc[mt][nt] = __builtin_amdgcn_mfma_f32_16x16x32_f16(af[mt], bf[nt], acc[mt][nt], 0, 0, 0);
    }

    // epilogue: D row = (l>>4)*4 + q (m-dim), col = l&15 (j-dim); store 4 m-consecutive f16
#pragma unroll
    for (int mt = 0; mt < 2; mt++)
#pragma unroll
        for (int nt = 0; nt < 8; nt++) {
            int j = j0 + 16 * nt + lr;
            int m = m0 + 32 * w + 16 * mt + 4 * lg;
            float bv = bsum[16 * nt + lr];
            h4_t o;
#pragma unroll
            for (int q = 0; q < 4; q++) o[q] = (_Float16)(acc[mt][nt][q] + bv);
            *(h4_t*)(Gp + (size_t)j * NM + m) = o;
        }
}

// ---------------- kernel 3: recurrence ----------------
// 256 threads/block (block = batch row b). Thread j owns gate rows j and j+256
// (f16 half2-packed W_hh in 128 VGPRs). h exchanged as f16[128] in LDS ->
// 16 broadcast ds_read_b128 + 128 v_dot2_f32_f16 per thread per step.
__global__ __launch_bounds__(256, 1) void k_lstm(const _Float16* __restrict__ Gp,
        const _Float16* __restrict__ whh_h, const float* __restrict__ plr,
        const float* __restrict__ unif_h,
        float* __restrict__ xout, float* __restrict__ hlast) {
    __shared__ _Float16 hd[128];
    __shared__ float gates[512];
    int b = blockIdx.x;
    int j = threadIdx.x;
    bool is_ig = (j < 128);   // rows {i_n, g_n}; else {f_n, o_n} — wave-uniform

    h2_t w0[64], w1[64];
    {
        const _Float16* wr0 = whh_h + (size_t)j * NH;
        const _Float16* wr1 = whh_h + (size_t)(j + 256) * NH;
#pragma unroll
        for (int i = 0; i < 16; i++) {
            h8_t a = *(const h8_t*)(wr0 + 8 * i);
            h8_t c = *(const h8_t*)(wr1 + 8 * i);
#pragma unroll
            for (int q = 0; q < 4; q++) {
                w0[4 * i + q] = (h2_t){a[2 * q], a[2 * q + 1]};
                w1[4 * i + q] = (h2_t){c[2 * q], c[2 * q + 1]};
            }
        }
    }

    float pr = sig(plr[0]);
    float h = 0.f, c = 0.f, msk = 0.f;
    if (j < 128) {
        float u  = unif_h[b * NH + j];
        float lg = logf(pr + F_EPS) - logf(1.f - pr + F_EPS)
                 + logf(u + F_EPS) - logf(1.f - u + F_EPS);
        float mk = 1.f - sig(lg / F_TEMP);
        msk = mk / (1.f - pr);
        hd[j] = (_Float16)0.f;
    }
    const _Float16* g0p = Gp + (size_t)j * NM + (size_t)b * NT;
    const _Float16* g1p = Gp + (size_t)(j + 256) * NM + (size_t)b * NT;
    __syncthreads();

    auto STEP = [&](float gA, float gB, int tcur) {
        float a0 = 0.f, a1 = 0.f, b0 = 0.f, b1 = 0.f;
#pragma unroll
        for (int i = 0; i < 16; i++) {
            h8_t hv = *(const h8_t*)(&hd[8 * i]);   // broadcast read
#pragma unroll
            for (int q = 0; q < 4; q++) {
                h2_t h2 = (h2_t){hv[2 * q], hv[2 * q + 1]};
                if (q & 1) {
                    a1 = FDOT2(h2, w0[4 * i + q], a1);
                    b1 = FDOT2(h2, w1[4 * i + q], b1);
                } else {
                    a0 = FDOT2(h2, w0[4 * i + q], a0);
                    b0 = FDOT2(h2, w1[4 * i + q], b0);
                }
            }
        }
        float sA = gA + a0 + a1;
        float sB = gB + b0 + b1;
        float actA = 1.f / (1.f + expf(-sA));                          // i or f
        float actB = is_ig ? tanhf(sB) : 1.f / (1.f + expf(-sB));      // g or o
        gates[j] = actA;
        gates[j + 256] = actB;
        __syncthreads();   // gates ready; hd reads done
        if (j < 128) {
            float ig = gates[j], fg = gates[j + 128];
            float gg = gates[j + 256], og = gates[j + 384];
            c = fg * c + ig * gg;
            h = og * tanhf(c);
            hd[j] = (_Float16)(h * msk);
            xout[((size_t)b * NT + tcur) * NH + j] = h;
        }
        __syncthreads();   // hd ready for next step
    };

    h2_t cg0 = *(const h2_t*)(g0p);
    h2_t cg1 = *(const h2_t*)(g1p);
    for (int t = 0; t < NT; t += 2) {
        h2_t ng0 = cg0, ng1 = cg1;
        if (t + 2 < NT) {
            ng0 = *(const h2_t*)(g0p + t + 2);
            ng1 = *(const h2_t*)(g1p + t + 2);
        }
        STEP((float)cg0[0], (float)cg1[0], t);
        STEP((float)cg0[1], (float)cg1[1], t + 1);
        cg0 = ng0; cg1 = ng1;
    }
    if (j < 128) hlast[(size_t)b * NH + j] = h;
}

extern "C" void kernel_launch(void* const* d_in, const int* in_sizes, int n_in,
                              void* d_out, int out_size, void* d_ws, size_t ws_size,
                              hipStream_t stream) {
    const float* x   = (const float*)d_in[0];
    const float* wih = (const float*)d_in[1];
    const float* whh = (const float*)d_in[2];
    const float* bih = (const float*)d_in[3];
    const float* bhh = (const float*)d_in[4];
    const float* pl  = (const float*)d_in[5];
    const float* plr = (const float*)d_in[6];
    const float* ux  = (const float*)d_in[7];
    const float* uh  = (const float*)d_in[8];

    float* out   = (float*)d_out;
    float* xout  = out;                                 // [B,T,H]
    float* hlast = out + (size_t)NB * NT * NH;          // [B,H]
    float* tail  = hlast + (size_t)NB * NH;             // reg, p, p_rec

    _Float16* G     = (_Float16*)d_ws;                               // [NG][NM] f16 = 128 MiB
    _Float16* wih_h = (_Float16*)((char*)d_ws + (size_t)NG * NM * 2);
    _Float16* whh_h = wih_h + (size_t)NG * ND;

    k_scalars<<<1, 512, 0, stream>>>(wih, whh, bih, bhh, pl, plr, tail);
    k_convert<<<64, 256, 0, stream>>>(wih, whh, wih_h, whh_h);

    dim3 gg(NM / 128, NG / 128);
    k_gemm<<<gg, 256, 0, stream>>>(x, wih_h, bih, bhh, pl, ux, G);

    k_lstm<<<NB, 256, 0, stream>>>(G, whh_h, plr, uh, xout, hlast);
}

// Round 3
// 507.841 us; speedup vs baseline: 2.3297x; 1.4408x over previous
//
#include <hip/hip_runtime.h>
#include <cstddef>

#define NB 256   // batch
#define NT 512   // time
#define ND 128   // input dim
#define NH 128   // hidden
#define NG 512   // 4*H
#define NM (NB * NT)   // 131072 rows of the input GEMM

constexpr float F_EPS  = 1e-7f;
constexpr float F_TEMP = 0.1f;

typedef _Float16 h2_t __attribute__((ext_vector_type(2)));
typedef _Float16 h4_t __attribute__((ext_vector_type(4)));
typedef _Float16 h8_t __attribute__((ext_vector_type(8)));
typedef float    fx4  __attribute__((ext_vector_type(4)));

#if defined(__has_builtin)
#  if __has_builtin(__builtin_amdgcn_fdot2)
#    define FDOT2(a, b, c) __builtin_amdgcn_fdot2((a), (b), (c), false)
#  endif
#endif
#ifndef FDOT2
#  define FDOT2(a, b, c) ((c) + (float)(a)[0] * (float)(b)[0] + (float)(a)[1] * (float)(b)[1])
#endif

__device__ __forceinline__ float sig(float x) { return 1.0f / (1.0f + expf(-x)); }

// ---------------- kernel 1: f32 -> f16 weight conversion + weight^2 sums ----------------
__global__ __launch_bounds__(256) void k_convert(const float* __restrict__ wih,
        const float* __restrict__ whh, _Float16* __restrict__ wih_h,
        _Float16* __restrict__ whh_h, float* __restrict__ partial) {
    int i = blockIdx.x * 256 + threadIdx.x;    // float4 index, 16384 total
    float4 a = ((const float4*)wih)[i];
    float4 b = ((const float4*)whh)[i];
    h4_t ah, bh;
    ah[0] = (_Float16)a.x; ah[1] = (_Float16)a.y; ah[2] = (_Float16)a.z; ah[3] = (_Float16)a.w;
    bh[0] = (_Float16)b.x; bh[1] = (_Float16)b.y; bh[2] = (_Float16)b.z; bh[3] = (_Float16)b.w;
    *(h4_t*)(wih_h + 4 * (size_t)i) = ah;
    *(h4_t*)(whh_h + 4 * (size_t)i) = bh;
    float sk = a.x * a.x + a.y * a.y + a.z * a.z + a.w * a.w;
    float sr = b.x * b.x + b.y * b.y + b.z * b.z + b.w * b.w;
    for (int off = 32; off; off >>= 1) {
        sk += __shfl_down(sk, off);
        sr += __shfl_down(sr, off);
    }
    if ((threadIdx.x & 63) == 0) {
        atomicAdd(partial + 0, sk);
        atomicAdd(partial + 1, sr);
    }
}

// ---------------- kernel 1b: finalize scalar regularization outputs ----------------
__global__ void k_tail(const float* __restrict__ bih, const float* __restrict__ bhh,
                       const float* __restrict__ pl, const float* __restrict__ plr,
                       const float* __restrict__ partial, float* __restrict__ out_tail) {
    __shared__ float red[8];
    int t = threadIdx.x;  // 512 threads
    float v = bih[t], w2 = bhh[t];
    float sb = v * v + w2 * w2;
    for (int off = 32; off; off >>= 1) sb += __shfl_down(sb, off);
    int wid = t >> 6, lane = t & 63;
    if (lane == 0) red[wid] = sb;
    __syncthreads();
    if (t == 0) {
        float SB = 0.f;
        for (int i = 0; i < 8; i++) SB += red[i];
        float SK = partial[0], SR = partial[1];
        float p  = sig(pl[0]);
        float pr = sig(plr[0]);
        float wr = 1e-6f * (SK / (1.f - p) + SR / (1.f - pr));
        float br = 1e-6f * SB;
        float ek = p * logf(p) + (1.f - p) * logf(1.f - p);
        float er = pr * logf(pr) + (1.f - pr) * logf(1.f - pr);
        float dr = 1e-5f * ((float)ND * ek + (float)NH * er);
        out_tail[0] = wr + br + dr;
        out_tail[1] = p;
        out_tail[2] = pr;
    }
}

// ---------------- kernel 2: f16 MFMA input GEMM (unchanged, proven) ----------------
// G'[j][m] (f16, m-major rows) = sum_k (x[m,k]*mask_x[b,k]/(1-p)) * Wih[j,k] + bih[j]+bhh[j]
__global__ __launch_bounds__(256, 2) void k_gemm(const float* __restrict__ x,
        const _Float16* __restrict__ wih_h, const float* __restrict__ bih,
        const float* __restrict__ bhh, const float* __restrict__ pl,
        const float* __restrict__ unif_x, _Float16* __restrict__ Gp) {
    __shared__ _Float16 Alds[128 * 128];
    __shared__ _Float16 Wlds[128 * 128];
    __shared__ float sx[128];
    __shared__ float bsum[128];
    int t  = threadIdx.x;
    int m0 = blockIdx.x * 128;           // row block (within one batch b: 128 | 512)
    int j0 = blockIdx.y * 128;           // gate-col block
    int b  = m0 >> 9;

    float p = sig(pl[0]);
    if (t < 128) {
        float u  = unif_x[b * ND + t];
        float lg = logf(p + F_EPS) - logf(1.f - p + F_EPS)
                 + logf(u + F_EPS) - logf(1.f - u + F_EPS);
        float mk = 1.f - sig(lg / F_TEMP);
        sx[t] = mk / (1.f - p);
    } else {
        int j = t - 128;
        bsum[j] = bih[j0 + j] + bhh[j0 + j];
    }
    __syncthreads();

#pragma unroll
    for (int i = 0; i < 8; i++) {
        int s   = i * 256 + t;
        int row = s >> 4;                 // 0..127
        int s16 = s & 15;                 // 16B slot within row
        const float4* xp = (const float4*)(x + (size_t)(m0 + row) * ND + s16 * 8);
        float4 v0 = xp[0], v1 = xp[1];
        float4 s0 = *(const float4*)(sx + s16 * 8);
        float4 s1 = *(const float4*)(sx + s16 * 8 + 4);
        h8_t hv;
        hv[0] = (_Float16)(v0.x * s0.x); hv[1] = (_Float16)(v0.y * s0.y);
        hv[2] = (_Float16)(v0.z * s0.z); hv[3] = (_Float16)(v0.w * s0.w);
        hv[4] = (_Float16)(v1.x * s1.x); hv[5] = (_Float16)(v1.y * s1.y);
        hv[6] = (_Float16)(v1.z * s1.z); hv[7] = (_Float16)(v1.w * s1.w);
        *(h8_t*)(&Alds[(size_t)row * 128 + ((s16 ^ (row & 7)) << 3)]) = hv;
        h8_t wv = *(const h8_t*)(wih_h + (size_t)(j0 + row) * ND + s16 * 8);
        *(h8_t*)(&Wlds[(size_t)row * 128 + ((s16 ^ (row & 7)) << 3)]) = wv;
    }
    __syncthreads();

    int w  = t >> 6, l = t & 63;
    int lr = l & 15, lg = l >> 4;
    fx4 acc[2][8] = {};
#pragma unroll
    for (int kk = 0; kk < 4; kk++) {
        h8_t af[2], bf[8];
#pragma unroll
        for (int mt = 0; mt < 2; mt++) {
            int r = 32 * w + 16 * mt + lr;
            af[mt] = *(const h8_t*)(&Alds[(size_t)r * 128 + (((4 * kk + lg) ^ (r & 7)) << 3)]);
        }
#pragma unroll
        for (int nt = 0; nt < 8; nt++) {
            int r = 16 * nt + lr;
            bf[nt] = *(const h8_t*)(&Wlds[(size_t)r * 128 + (((4 * kk + lg) ^ (r & 7)) << 3)]);
        }
#pragma unroll
        for (int mt = 0; mt < 2; mt++)
#pragma unroll
            for (int nt = 0; nt < 8; nt++)
                acc[mt][nt] = __builtin_amdgcn_mfma_f32_16x16x32_f16(af[mt], bf[nt], acc[mt][nt], 0, 0, 0);
    }

#pragma unroll
    for (int mt = 0; mt < 2; mt++)
#pragma unroll
        for (int nt = 0; nt < 8; nt++) {
            int j = j0 + 16 * nt + lr;
            int m = m0 + 32 * w + 16 * mt + 4 * lg;
            float bv = bsum[16 * nt + lr];
            h4_t o;
#pragma unroll
            for (int q = 0; q < 4; q++) o[q] = (_Float16)(acc[mt][nt][q] + bv);
            *(h4_t*)(Gp + (size_t)j * NM + m) = o;
        }
}

// ---------------- kernel 3: recurrence with LDS-staged G windows ----------------
// 256 threads/block (block = batch b). Thread j owns gate rows j and j+256.
// G staged through a double-buffered [2][32][512] f16 LDS window: bulk 64B-line
// loads issued one full window ahead (latency hidden), per-step reads are 2
// ds_read_u16. hd exchange + fdot2 matvec as before.
#define LWIN 32
__global__ __launch_bounds__(256, 1) void k_lstm(const _Float16* __restrict__ Gp,
        const _Float16* __restrict__ whh_h, const float* __restrict__ plr,
        const float* __restrict__ unif_h,
        float* __restrict__ xout, float* __restrict__ hlast) {
    __shared__ _Float16 hd[128];
    __shared__ float gates[512];
    __shared__ _Float16 Gw[2][LWIN][512];
    int b = blockIdx.x;
    int j = threadIdx.x;
    bool is_ig = (j < 128);   // rows {i_n, g_n}; else {f_n, o_n} — wave-uniform

    h2_t w0[64], w1[64];
    {
        const _Float16* wr0 = whh_h + (size_t)j * NH;
        const _Float16* wr1 = whh_h + (size_t)(j + 256) * NH;
#pragma unroll
        for (int i = 0; i < 16; i++) {
            h8_t a = *(const h8_t*)(wr0 + 8 * i);
            h8_t c = *(const h8_t*)(wr1 + 8 * i);
#pragma unroll
            for (int q = 0; q < 4; q++) {
                w0[4 * i + q] = (h2_t){a[2 * q], a[2 * q + 1]};
                w1[4 * i + q] = (h2_t){c[2 * q], c[2 * q + 1]};
            }
        }
    }

    float pr = sig(plr[0]);
    float h = 0.f, c = 0.f, msk = 0.f;
    if (j < 128) {
        float u  = unif_h[b * NH + j];
        float lg = logf(pr + F_EPS) - logf(1.f - pr + F_EPS)
                 + logf(u + F_EPS) - logf(1.f - u + F_EPS);
        float mk = 1.f - sig(lg / F_TEMP);
        msk = mk / (1.f - pr);
        hd[j] = (_Float16)0.f;
    }

    const _Float16* g0p = Gp + (size_t)j * NM + (size_t)b * NT;
    const _Float16* g1p = Gp + (size_t)(j + 256) * NM + (size_t)b * NT;

    h8_t q0[4], q1[4];
    auto LOADW = [&](int t0) {
#pragma unroll
        for (int r = 0; r < 4; r++) {
            q0[r] = *(const h8_t*)(g0p + t0 + 8 * r);
            q1[r] = *(const h8_t*)(g1p + t0 + 8 * r);
        }
    };
    auto WRITEW = [&](int bf) {
#pragma unroll
        for (int r = 0; r < 4; r++)
#pragma unroll
            for (int e = 0; e < 8; e++) {
                Gw[bf][8 * r + e][j]       = q0[r][e];
                Gw[bf][8 * r + e][j + 256] = q1[r][e];
            }
    };

    LOADW(0);
    WRITEW(0);
    LOADW(LWIN);              // in flight during window 0
    __syncthreads();          // buf0 + hd ready

    for (int win = 0; win < NT / LWIN; win++) {
        int cur = win & 1;
        if (win + 1 < NT / LWIN) {
            WRITEW(cur ^ 1);                       // stage window win+1 (regs loaded ~1 window ago)
            if (win + 2 < NT / LWIN) LOADW(LWIN * (win + 2));  // issue loads for win+2
        }
        for (int tw = 0; tw < LWIN; tw++) {
            float gA = (float)Gw[cur][tw][j];
            float gB = (float)Gw[cur][tw][j + 256];
            float a0 = 0.f, a1 = 0.f, b0 = 0.f, b1 = 0.f;
#pragma unroll
            for (int i = 0; i < 16; i++) {
                h8_t hv = *(const h8_t*)(&hd[8 * i]);   // broadcast read
#pragma unroll
                for (int q = 0; q < 4; q++) {
                    h2_t h2 = (h2_t){hv[2 * q], hv[2 * q + 1]};
                    if (q & 1) {
                        a1 = FDOT2(h2, w0[4 * i + q], a1);
                        b1 = FDOT2(h2, w1[4 * i + q], b1);
                    } else {
                        a0 = FDOT2(h2, w0[4 * i + q], a0);
                        b0 = FDOT2(h2, w1[4 * i + q], b0);
                    }
                }
            }
            float sA = gA + a0 + a1;
            float sB = gB + b0 + b1;
            float actA = 1.f / (1.f + expf(-sA));                          // i or f
            float actB = is_ig ? tanhf(sB) : 1.f / (1.f + expf(-sB));      // g or o
            gates[j] = actA;
            gates[j + 256] = actB;
            __syncthreads();   // gates ready; hd reads done
            if (j < 128) {
                float ig = gates[j], fg = gates[j + 128];
                float gg = gates[j + 256], og = gates[j + 384];
                c = fg * c + ig * gg;
                h = og * tanhf(c);
                hd[j] = (_Float16)(h * msk);
                xout[((size_t)b * NT + (win * LWIN + tw)) * NH + j] = h;
            }
            __syncthreads();   // hd ready for next step
        }
    }
    if (j < 128) hlast[(size_t)b * NH + j] = h;
}

extern "C" void kernel_launch(void* const* d_in, const int* in_sizes, int n_in,
                              void* d_out, int out_size, void* d_ws, size_t ws_size,
                              hipStream_t stream) {
    const float* x   = (const float*)d_in[0];
    const float* wih = (const float*)d_in[1];
    const float* whh = (const float*)d_in[2];
    const float* bih = (const float*)d_in[3];
    const float* bhh = (const float*)d_in[4];
    const float* pl  = (const float*)d_in[5];
    const float* plr = (const float*)d_in[6];
    const float* ux  = (const float*)d_in[7];
    const float* uh  = (const float*)d_in[8];

    float* out   = (float*)d_out;
    float* xout  = out;                                 // [B,T,H]
    float* hlast = out + (size_t)NB * NT * NH;          // [B,H]
    float* tail  = hlast + (size_t)NB * NH;             // reg, p, p_rec

    _Float16* G     = (_Float16*)d_ws;                               // [NG][NM] f16 = 128 MiB
    _Float16* wih_h = (_Float16*)((char*)d_ws + (size_t)NG * NM * 2);
    _Float16* whh_h = wih_h + (size_t)NG * ND;
    float*    partial = (float*)(whh_h + (size_t)NG * NH);           // 2 floats

    hipMemsetAsync(partial, 0, 2 * sizeof(float), stream);

    k_convert<<<64, 256, 0, stream>>>(wih, whh, wih_h, whh_h, partial);

    dim3 gg(NM / 128, NG / 128);
    k_gemm<<<gg, 256, 0, stream>>>(x, wih_h, bih, bhh, pl, ux, G);

    k_tail<<<1, 512, 0, stream>>>(bih, bhh, pl, plr, partial, tail);

    k_lstm<<<NB, 256, 0, stream>>>(G, whh_h, plr, uh, xout, hlast);
}

// Round 4
// 372.480 us; speedup vs baseline: 3.1763x; 1.3634x over previous
//
#include <hip/hip_runtime.h>
#include <cstddef>

#define NB 256   // batch
#define NT 512   // time
#define ND 128   // input dim
#define NH 128   // hidden
#define NG 512   // 4*H
#define NM (NB * NT)   // 131072 rows of the input GEMM

constexpr float F_EPS  = 1e-7f;
constexpr float F_TEMP = 0.1f;

typedef _Float16 h2_t __attribute__((ext_vector_type(2)));
typedef _Float16 h4_t __attribute__((ext_vector_type(4)));
typedef _Float16 h8_t __attribute__((ext_vector_type(8)));
typedef float    fx4  __attribute__((ext_vector_type(4)));

#if defined(__has_builtin)
#  if __has_builtin(__builtin_amdgcn_fdot2)
#    define FDOT2(a, b, c) __builtin_amdgcn_fdot2((a), (b), (c), false)
#  endif
#endif
#ifndef FDOT2
#  define FDOT2(a, b, c) ((c) + (float)(a)[0] * (float)(b)[0] + (float)(a)[1] * (float)(b)[1])
#endif

__device__ __forceinline__ float fexp2(float x) {
#if defined(__has_builtin)
#  if __has_builtin(__builtin_amdgcn_exp2f)
    return __builtin_amdgcn_exp2f(x);
#  else
    return exp2f(x);
#  endif
#else
    return exp2f(x);
#endif
}
__device__ __forceinline__ float frcp(float x) {
#if defined(__has_builtin)
#  if __has_builtin(__builtin_amdgcn_rcpf)
    return __builtin_amdgcn_rcpf(x);
#  else
    return 1.0f / x;
#  endif
#else
    return 1.0f / x;
#endif
}
// sigmoid(x) = 1/(1+2^(-x*log2e))
__device__ __forceinline__ float fsig(float x) {
    return frcp(1.0f + fexp2(x * -1.44269504088896f));
}
// tanh(x) = 1 - 2/(2^(2x*log2e)+1)
__device__ __forceinline__ float ftanh(float x) {
    return 1.0f - 2.0f * frcp(1.0f + fexp2(x * 2.88539008177793f));
}
__device__ __forceinline__ float sig(float x) { return 1.0f / (1.0f + expf(-x)); }

// LDS-ordering-only barrier: does NOT drain vmcnt (global loads/stores stay in
// flight). lgkmcnt(0) orders our ds_writes before the barrier; sched_barrier
// pins it (rule #18).
__device__ __forceinline__ void bar_lds() {
    asm volatile("s_waitcnt lgkmcnt(0)" ::: "memory");
    __builtin_amdgcn_sched_barrier(0);
    __builtin_amdgcn_s_barrier();
}

// ---------------- kernel 1: f32 -> f16 weight conversion + weight^2 sums ----------------
__global__ __launch_bounds__(256) void k_convert(const float* __restrict__ wih,
        const float* __restrict__ whh, _Float16* __restrict__ wih_h,
        _Float16* __restrict__ whh_h, float* __restrict__ partial) {
    int i = blockIdx.x * 256 + threadIdx.x;    // float4 index, 16384 total
    float4 a = ((const float4*)wih)[i];
    float4 b = ((const float4*)whh)[i];
    h4_t ah, bh;
    ah[0] = (_Float16)a.x; ah[1] = (_Float16)a.y; ah[2] = (_Float16)a.z; ah[3] = (_Float16)a.w;
    bh[0] = (_Float16)b.x; bh[1] = (_Float16)b.y; bh[2] = (_Float16)b.z; bh[3] = (_Float16)b.w;
    *(h4_t*)(wih_h + 4 * (size_t)i) = ah;
    *(h4_t*)(whh_h + 4 * (size_t)i) = bh;
    float sk = a.x * a.x + a.y * a.y + a.z * a.z + a.w * a.w;
    float sr = b.x * b.x + b.y * b.y + b.z * b.z + b.w * b.w;
    for (int off = 32; off; off >>= 1) {
        sk += __shfl_down(sk, off);
        sr += __shfl_down(sr, off);
    }
    if ((threadIdx.x & 63) == 0) {
        atomicAdd(partial + 0, sk);
        atomicAdd(partial + 1, sr);
    }
}

// ---------------- kernel 1b: finalize scalar regularization outputs ----------------
__global__ void k_tail(const float* __restrict__ bih, const float* __restrict__ bhh,
                       const float* __restrict__ pl, const float* __restrict__ plr,
                       const float* __restrict__ partial, float* __restrict__ out_tail) {
    __shared__ float red[8];
    int t = threadIdx.x;  // 512 threads
    float v = bih[t], w2 = bhh[t];
    float sb = v * v + w2 * w2;
    for (int off = 32; off; off >>= 1) sb += __shfl_down(sb, off);
    int wid = t >> 6, lane = t & 63;
    if (lane == 0) red[wid] = sb;
    __syncthreads();
    if (t == 0) {
        float SB = 0.f;
        for (int i = 0; i < 8; i++) SB += red[i];
        float SK = partial[0], SR = partial[1];
        float p  = sig(pl[0]);
        float pr = sig(plr[0]);
        float wr = 1e-6f * (SK / (1.f - p) + SR / (1.f - pr));
        float br = 1e-6f * SB;
        float ek = p * logf(p) + (1.f - p) * logf(1.f - p);
        float er = pr * logf(pr) + (1.f - pr) * logf(1.f - pr);
        float dr = 1e-5f * ((float)ND * ek + (float)NH * er);
        out_tail[0] = wr + br + dr;
        out_tail[1] = p;
        out_tail[2] = pr;
    }
}

// ---------------- kernel 2: f16 MFMA input GEMM (unchanged, proven) ----------------
__global__ __launch_bounds__(256, 2) void k_gemm(const float* __restrict__ x,
        const _Float16* __restrict__ wih_h, const float* __restrict__ bih,
        const float* __restrict__ bhh, const float* __restrict__ pl,
        const float* __restrict__ unif_x, _Float16* __restrict__ Gp) {
    __shared__ _Float16 Alds[128 * 128];
    __shared__ _Float16 Wlds[128 * 128];
    __shared__ float sx[128];
    __shared__ float bsum[128];
    int t  = threadIdx.x;
    int m0 = blockIdx.x * 128;           // row block (within one batch b: 128 | 512)
    int j0 = blockIdx.y * 128;           // gate-col block
    int b  = m0 >> 9;

    float p = sig(pl[0]);
    if (t < 128) {
        float u  = unif_x[b * ND + t];
        float lg = logf(p + F_EPS) - logf(1.f - p + F_EPS)
                 + logf(u + F_EPS) - logf(1.f - u + F_EPS);
        float mk = 1.f - sig(lg / F_TEMP);
        sx[t] = mk / (1.f - p);
    } else {
        int j = t - 128;
        bsum[j] = bih[j0 + j] + bhh[j0 + j];
    }
    __syncthreads();

#pragma unroll
    for (int i = 0; i < 8; i++) {
        int s   = i * 256 + t;
        int row = s >> 4;                 // 0..127
        int s16 = s & 15;                 // 16B slot within row
        const float4* xp = (const float4*)(x + (size_t)(m0 + row) * ND + s16 * 8);
        float4 v0 = xp[0], v1 = xp[1];
        float4 s0 = *(const float4*)(sx + s16 * 8);
        float4 s1 = *(const float4*)(sx + s16 * 8 + 4);
        h8_t hv;
        hv[0] = (_Float16)(v0.x * s0.x); hv[1] = (_Float16)(v0.y * s0.y);
        hv[2] = (_Float16)(v0.z * s0.z); hv[3] = (_Float16)(v0.w * s0.w);
        hv[4] = (_Float16)(v1.x * s1.x); hv[5] = (_Float16)(v1.y * s1.y);
        hv[6] = (_Float16)(v1.z * s1.z); hv[7] = (_Float16)(v1.w * s1.w);
        *(h8_t*)(&Alds[(size_t)row * 128 + ((s16 ^ (row & 7)) << 3)]) = hv;
        h8_t wv = *(const h8_t*)(wih_h + (size_t)(j0 + row) * ND + s16 * 8);
        *(h8_t*)(&Wlds[(size_t)row * 128 + ((s16 ^ (row & 7)) << 3)]) = wv;
    }
    __syncthreads();

    int w  = t >> 6, l = t & 63;
    int lr = l & 15, lg = l >> 4;
    fx4 acc[2][8] = {};
#pragma unroll
    for (int kk = 0; kk < 4; kk++) {
        h8_t af[2], bf[8];
#pragma unroll
        for (int mt = 0; mt < 2; mt++) {
            int r = 32 * w + 16 * mt + lr;
            af[mt] = *(const h8_t*)(&Alds[(size_t)r * 128 + (((4 * kk + lg) ^ (r & 7)) << 3)]);
        }
#pragma unroll
        for (int nt = 0; nt < 8; nt++) {
            int r = 16 * nt + lr;
            bf[nt] = *(const h8_t*)(&Wlds[(size_t)r * 128 + (((4 * kk + lg) ^ (r & 7)) << 3)]);
        }
#pragma unroll
        for (int mt = 0; mt < 2; mt++)
#pragma unroll
            for (int nt = 0; nt < 8; nt++)
                acc[mt][nt] = __builtin_amdgcn_mfma_f32_16x16x32_f16(af[mt], bf[nt], acc[mt][nt], 0, 0, 0);
    }

#pragma unroll
    for (int mt = 0; mt < 2; mt++)
#pragma unroll
        for (int nt = 0; nt < 8; nt++) {
            int j = j0 + 16 * nt + lr;
            int m = m0 + 32 * w + 16 * mt + 4 * lg;
            float bv = bsum[16 * nt + lr];
            h4_t o;
#pragma unroll
            for (int q = 0; q < 4; q++) o[q] = (_Float16)(acc[mt][nt][q] + bv);
            *(h4_t*)(Gp + (size_t)j * NM + m) = o;
        }
}

// ---------------- kernel 3: recurrence, 512 threads (1 gate row/thread) ----------------
// Block = batch row b; thread j in [0,512) owns gate row j (W_hh row in 64 h2
// VGPRs). G stream lives in registers (1 h8 per 8 steps, double-buffered, all
// static indices). Per step: 16 broadcast ds_read_b128 of hd + 64 fdot2, fast
// exp2-based activations, two LDS-only barriers (no vmcnt drain -> xout stores
// and G prefetch loads stay in flight across barriers).
__global__ __launch_bounds__(512, 2) void k_lstm(const _Float16* __restrict__ Gp,
        const _Float16* __restrict__ whh_h, const float* __restrict__ plr,
        const float* __restrict__ unif_h,
        float* __restrict__ xout, float* __restrict__ hlast) {
    __shared__ _Float16 hd[128];
    __shared__ float gates[512];
    int b = blockIdx.x;
    int j = threadIdx.x;
    int gate = j >> 7;                 // 0:i 1:f 2:g 3:o — wave-uniform

    h2_t w[64];
    {
        const _Float16* wr = whh_h + (size_t)j * NH;
#pragma unroll
        for (int i = 0; i < 16; i++) {
            h8_t a = *(const h8_t*)(wr + 8 * i);
#pragma unroll
            for (int q = 0; q < 4; q++)
                w[4 * i + q] = (h2_t){a[2 * q], a[2 * q + 1]};
        }
    }

    float pr = sig(plr[0]);
    float h = 0.f, c = 0.f, msk = 0.f;
    if (j < 128) {
        float u  = unif_h[b * NH + j];
        float lg = logf(pr + F_EPS) - logf(1.f - pr + F_EPS)
                 + logf(u + F_EPS) - logf(1.f - u + F_EPS);
        float mk = 1.f - sig(lg / F_TEMP);
        msk = mk / (1.f - pr);
        hd[j] = (_Float16)0.f;
    }

    const _Float16* gp = Gp + (size_t)j * NM + (size_t)b * NT;
    float* xo = xout + (size_t)b * NT * NH + j;   // valid use only when j<128

    h8_t gcur = *(const h8_t*)(gp);
    __syncthreads();          // hd init visible (full barrier once is fine)

    for (int w8 = 0; w8 < NT / 8; w8++) {
        h8_t gnx = gcur;
        if (w8 + 1 < NT / 8) gnx = *(const h8_t*)(gp + 8 * (w8 + 1));  // in flight ~8 steps
#pragma unroll
        for (int e = 0; e < 8; e++) {
            float a0 = 0.f, a1 = 0.f, a2 = 0.f, a3 = 0.f;
#pragma unroll
            for (int i = 0; i < 16; i++) {
                h8_t hv = *(const h8_t*)(&hd[8 * i]);   // broadcast read
                a0 = FDOT2(((h2_t){hv[0], hv[1]}), w[4 * i + 0], a0);
                a1 = FDOT2(((h2_t){hv[2], hv[3]}), w[4 * i + 1], a1);
                a2 = FDOT2(((h2_t){hv[4], hv[5]}), w[4 * i + 2], a2);
                a3 = FDOT2(((h2_t){hv[6], hv[7]}), w[4 * i + 3], a3);
            }
            float s = (float)gcur[e] + ((a0 + a1) + (a2 + a3));
            gates[j] = (gate == 2) ? ftanh(s) : fsig(s);
            bar_lds();             // gates ready; hd reads of this step done
            if (j < 128) {
                float ig = gates[j],       fg = gates[j + 128];
                float gg = gates[j + 256], og = gates[j + 384];
                c = fg * c + ig * gg;
                h = og * ftanh(c);
                hd[j] = (_Float16)(h * msk);
                xo[(size_t)(8 * w8 + e) * NH] = h;   // store: never drained by barriers
            }
            bar_lds();             // hd ready for next step
        }
        gcur = gnx;
    }
    if (j < 128) hlast[(size_t)b * NH + j] = h;
}

extern "C" void kernel_launch(void* const* d_in, const int* in_sizes, int n_in,
                              void* d_out, int out_size, void* d_ws, size_t ws_size,
                              hipStream_t stream) {
    const float* x   = (const float*)d_in[0];
    const float* wih = (const float*)d_in[1];
    const float* whh = (const float*)d_in[2];
    const float* bih = (const float*)d_in[3];
    const float* bhh = (const float*)d_in[4];
    const float* pl  = (const float*)d_in[5];
    const float* plr = (const float*)d_in[6];
    const float* ux  = (const float*)d_in[7];
    const float* uh  = (const float*)d_in[8];

    float* out   = (float*)d_out;
    float* xout  = out;                                 // [B,T,H]
    float* hlast = out + (size_t)NB * NT * NH;          // [B,H]
    float* tail  = hlast + (size_t)NB * NH;             // reg, p, p_rec

    _Float16* G     = (_Float16*)d_ws;                               // [NG][NM] f16 = 128 MiB
    _Float16* wih_h = (_Float16*)((char*)d_ws + (size_t)NG * NM * 2);
    _Float16* whh_h = wih_h + (size_t)NG * ND;
    float*    partial = (float*)(whh_h + (size_t)NG * NH);           // 2 floats

    hipMemsetAsync(partial, 0, 2 * sizeof(float), stream);

    k_convert<<<64, 256, 0, stream>>>(wih, whh, wih_h, whh_h, partial);

    dim3 gg(NM / 128, NG / 128);
    k_gemm<<<gg, 256, 0, stream>>>(x, wih_h, bih, bhh, pl, ux, G);

    k_tail<<<1, 512, 0, stream>>>(bih, bhh, pl, plr, partial, tail);

    k_lstm<<<NB, 512, 0, stream>>>(G, whh_h, plr, uh, xout, hlast);
}